// Round 2
// baseline (2947.990 us; speedup 1.0000x reference)
//
#include <hip/hip_runtime.h>
#include <hip/hip_bf16.h>
#include <stdint.h>

// Problem constants (from reference)
#define NND   100000      // nodes
#define NED   400000      // edges
#define KD    512         // DIN
#define ND    512         // DOUT
#define MPAD  100096      // 782 * 128 (M padded to tile)
#define PDROP 0.1f
#define INV_KEEP (1.0f/0.9f)

typedef __attribute__((ext_vector_type(4))) float f32x4;
typedef __attribute__((ext_vector_type(8))) short short8;

// ---- ws layout (bytes) ----
// [0)              xd_bf16 [MPAD][512]   = 102,498,304
// [XD_END)         wt_bf16 [512][512]    = 524,288   (W^T, bf16)
// [WT_END)         hp_bf16 [MPAD][512]   = 102,498,304 (h' = dinv*xd@W)
// [HP_END)         deg_u32 [NND]         = 400,000
// [DEG_END)        dinv_f32[NND]         = 400,000
#define XD_OFF   0
#define WT_OFF   102498304
#define HP_OFF   103022592
#define DEG_OFF  205520896
#define DINV_OFF 205920896
// total ~206.3 MB

__device__ __forceinline__ unsigned short f2bf(float f) {
  // RNE float->bf16 (finite inputs)
  unsigned int x = __float_as_uint(f);
  unsigned int r = (x + 0x7fffu + ((x >> 16) & 1u)) >> 16;
  return (unsigned short)r;
}
__device__ __forceinline__ float bf2f(unsigned short u) {
  return __uint_as_float(((unsigned int)u) << 16);
}

__device__ __forceinline__ void gload_lds16(const void* g, void* l) {
  __builtin_amdgcn_global_load_lds(
      (const __attribute__((address_space(1))) unsigned int*)g,
      (__attribute__((address_space(3))) unsigned int*)l,
      16, 0, 0);
}

// ---------- P1: fused dropout + f32->bf16, zero-pad rows [NND, MPAD) ----------
__global__ void k_dropout(const float* __restrict__ x, const float* __restrict__ dm,
                          unsigned short* __restrict__ xd) {
  int idx = blockIdx.x * 256 + threadIdx.x;   // one float4 per thread
  int row = idx >> 7;
  int q = (idx & 127) << 2;
  size_t o = (size_t)row * KD + q;
  ushort4 u;
  if (row < NND) {
    float4 xv = *(const float4*)(x + o);
    float4 mv = *(const float4*)(dm + o);
    float a0 = (mv.x >= PDROP) ? xv.x * INV_KEEP : 0.0f;
    float a1 = (mv.y >= PDROP) ? xv.y * INV_KEEP : 0.0f;
    float a2 = (mv.z >= PDROP) ? xv.z * INV_KEEP : 0.0f;
    float a3 = (mv.w >= PDROP) ? xv.w * INV_KEEP : 0.0f;
    u.x = f2bf(a0); u.y = f2bf(a1); u.z = f2bf(a2); u.w = f2bf(a3);
  } else {
    u.x = 0; u.y = 0; u.z = 0; u.w = 0;
  }
  *(ushort4*)(xd + o) = u;
}

// ---------- P2: W^T in bf16 (tiny: 512x512) ----------
__global__ void k_wt(const float* __restrict__ W, unsigned short* __restrict__ wt) {
  int idx = blockIdx.x * 256 + threadIdx.x;   // idx = n*512 + k
  int n = idx >> 9, k = idx & 511;
  wt[idx] = f2bf(W[k * 512 + n]);
}

// ---------- degree / dinv ----------
__global__ void k_deg_init(unsigned int* deg) {
  int i = blockIdx.x * 256 + threadIdx.x;
  if (i < NND) deg[i] = 1u;                   // self-loop
}
__global__ void k_deg_count(const int* __restrict__ ei, unsigned int* deg) {
  int e = blockIdx.x * 256 + threadIdx.x;
  if (e < NED) atomicAdd(&deg[ei[NED + e]], 1u);   // col = destination
}
__global__ void k_dinv(const unsigned int* __restrict__ deg, float* __restrict__ dinv) {
  int i = blockIdx.x * 256 + threadIdx.x;
  if (i < NND) dinv[i] = rsqrtf((float)deg[i]);   // deg >= 1 always
}

// ---------- bf16 MFMA GEMM: h' = dinv * (xd @ Wt^T); writes hp (bf16) and out (f32) ----------
// m97-style: 128x128 tile, BK=64, 4 waves (each 64x64 = 4x4 of 16x16x32 frags),
// global_load_lds width 16, single-buffered LDS.
__launch_bounds__(256, 2)
__global__ void k_gemm(const unsigned short* __restrict__ xd,
                       const unsigned short* __restrict__ wt,
                       const float* __restrict__ dinv,
                       unsigned short* __restrict__ hp,
                       float* __restrict__ out) {
  __shared__ unsigned short As[128 * 64];
  __shared__ unsigned short Bs[128 * 64];

  int bid = blockIdx.x;
  int wg = (bid & 7) * 391 + (bid >> 3);      // XCD-chunked bijective swizzle (3128 = 8*391)
  int mt = wg >> 2, nt = wg & 3;              // n fastest -> A-panel L2 reuse per XCD
  int t = threadIdx.x, wave = t >> 6, lane = t & 63;
  int wr = wave >> 1, wc = wave & 1;

  f32x4 zero = {0.f, 0.f, 0.f, 0.f};
  f32x4 acc[4][4];
  for (int m = 0; m < 4; ++m)
    for (int n = 0; n < 4; ++n) acc[m][n] = zero;

  const int m_base = mt * 128;
  const int n_base = nt * 128;
  const int crow = lane >> 3;        // 0..7 within 8-row chunk
  const int ccol = (lane & 7) * 8;   // element offset within 64-wide row

  for (int kt = 0; kt < 8; ++kt) {
    int k0 = kt * 64;
    // stage A and B: 16 chunks each of 1KB (8 rows x 64 bf16); 4 issues x 4 waves
    for (int i = 0; i < 4; ++i) {
      int c = i * 4 + wave;
      int r = c * 8 + crow;
      gload_lds16(xd + (size_t)(m_base + r) * KD + k0 + ccol, As + c * 512);
      gload_lds16(wt + (size_t)(n_base + r) * KD + k0 + ccol, Bs + c * 512);
    }
    __syncthreads();   // compiler drains vmcnt before barrier
    for (int kk = 0; kk < 2; ++kk) {
      int ko = kk * 32 + (lane >> 4) * 8;
      short8 a[4], b[4];
      for (int m = 0; m < 4; ++m)
        a[m] = *(const short8*)(As + (wr * 64 + m * 16 + (lane & 15)) * 64 + ko);
      for (int n = 0; n < 4; ++n)
        b[n] = *(const short8*)(Bs + (wc * 64 + n * 16 + (lane & 15)) * 64 + ko);
      for (int m = 0; m < 4; ++m)
        for (int n = 0; n < 4; ++n)
          acc[m][n] = __builtin_amdgcn_mfma_f32_16x16x32_bf16(a[m], b[n], acc[m][n], 0, 0, 0);
    }
    __syncthreads();
  }

  // epilogue: C/D layout col=lane&15, row=(lane>>4)*4+j
  int c0 = n_base + wc * 64;
  for (int m = 0; m < 4; ++m) {
    int grb = m_base + wr * 64 + m * 16 + (lane >> 4) * 4;
    for (int j = 0; j < 4; ++j) {
      int gr = grb + j;
      if (gr < NND) {
        float dv = dinv[gr];
        size_t ro = (size_t)gr * ND;
        for (int n = 0; n < 4; ++n) {
          int gc = c0 + n * 16 + (lane & 15);
          float v = acc[m][n][j] * dv;
          out[ro + gc] = v;            // self-loop contribution (pre final scale)
          hp[ro + gc] = f2bf(v);       // h' for the scatter phase
        }
      }
    }
  }
}

// ---------- scatter: out[dst] += h'[src] over edges ----------
__global__ void k_scatter(const int* __restrict__ ei,
                          const unsigned short* __restrict__ hp,
                          float* __restrict__ out) {
  long long idx = (long long)blockIdx.x * 256 + threadIdx.x;
  int e = (int)(idx >> 7);
  int q = ((int)idx & 127) * 4;
  int src = ei[e];
  int dst = ei[NED + e];
  ushort4 hv = *(const ushort4*)(hp + (size_t)src * ND + q);
  float* op = out + (size_t)dst * ND + q;
  unsafeAtomicAdd(op + 0, bf2f(hv.x));
  unsafeAtomicAdd(op + 1, bf2f(hv.y));
  unsafeAtomicAdd(op + 2, bf2f(hv.z));
  unsafeAtomicAdd(op + 3, bf2f(hv.w));
}

// ---------- final: out = dinv[i]*out + b ----------
__global__ void k_final(const float* __restrict__ dinv, const float* __restrict__ b,
                        float* __restrict__ out) {
  int idx = blockIdx.x * 256 + threadIdx.x;   // one float4 per thread
  int i = idx >> 7, q = (idx & 127) << 2;
  size_t o = (size_t)i * ND + q;
  float4 v = *(const float4*)(out + o);
  float dv = dinv[i];
  float4 bb = *(const float4*)(b + q);
  v.x = v.x * dv + bb.x;
  v.y = v.y * dv + bb.y;
  v.z = v.z * dv + bb.z;
  v.w = v.w * dv + bb.w;
  *(float4*)(out + o) = v;
}

extern "C" void kernel_launch(void* const* d_in, const int* in_sizes, int n_in,
                              void* d_out, int out_size, void* d_ws, size_t ws_size,
                              hipStream_t stream) {
  const float* x  = (const float*)d_in[0];
  const int*   ei = (const int*)d_in[1];     // int64 in reference -> int32 here
  const float* W  = (const float*)d_in[2];
  const float* b  = (const float*)d_in[3];
  const float* dm = (const float*)d_in[4];
  float* out = (float*)d_out;

  char* ws = (char*)d_ws;
  unsigned short* xd   = (unsigned short*)(ws + XD_OFF);
  unsigned short* wt   = (unsigned short*)(ws + WT_OFF);
  unsigned short* hp   = (unsigned short*)(ws + HP_OFF);
  unsigned int*   deg  = (unsigned int*)(ws + DEG_OFF);
  float*          dinv = (float*)(ws + DINV_OFF);

  hipLaunchKernelGGL(k_dropout,   dim3(50048),  dim3(256), 0, stream, x, dm, xd);
  hipLaunchKernelGGL(k_wt,        dim3(1024),   dim3(256), 0, stream, W, wt);
  hipLaunchKernelGGL(k_deg_init,  dim3(391),    dim3(256), 0, stream, deg);
  hipLaunchKernelGGL(k_deg_count, dim3(1563),   dim3(256), 0, stream, ei, deg);
  hipLaunchKernelGGL(k_dinv,      dim3(391),    dim3(256), 0, stream, deg, dinv);
  hipLaunchKernelGGL(k_gemm,      dim3(3128),   dim3(256), 0, stream, xd, wt, dinv, hp, out);
  hipLaunchKernelGGL(k_scatter,   dim3(200000), dim3(256), 0, stream, ei, hp, out);
  hipLaunchKernelGGL(k_final,     dim3(50000),  dim3(256), 0, stream, dinv, b, out);
}

// Round 3
// 347.807 us; speedup vs baseline: 8.4759x; 8.4759x over previous
//
#include <hip/hip_runtime.h>
#include <hip/hip_bf16.h>
#include <stdint.h>

// Problem constants (from reference)
#define NND   100000      // nodes
#define NED   400000      // edges
#define KD    512         // DIN
#define ND    512         // DOUT
#define MPAD  100096      // 782 * 128 (M padded to tile)
#define PDROP 0.1f
#define INV_KEEP (1.0f/0.9f)

typedef __attribute__((ext_vector_type(4))) float f32x4;
typedef __attribute__((ext_vector_type(8))) short short8;
typedef __attribute__((ext_vector_type(8))) unsigned short ushort8;

// ---- ws layout (bytes) ----
#define XD_OFF   0            // xd_bf16 [MPAD][512]  = 102,498,304
#define WT_OFF   102498304    // wt_bf16 [512][512]   = 524,288
#define HP_OFF   103022592    // hp_bf16 [MPAD][512]  = 102,498,304
#define DEG_OFF  205520896    // deg_u32 [NND]        = 400,000 (edge-only in-degree)
#define DINV_OFF 205920896    // dinv_f32[NND]        = 400,000
#define OFFS_OFF 206320896    // offs_u32[NND]        = 400,000 (CSR offsets -> cursors -> ends)
#define SRCS_OFF 206720896    // srcs_i32[NED]        = 1,600,000
#define BSUM_OFF 208320896    // block sums           = 2,048
// total ~208.3 MB

__device__ __forceinline__ unsigned short f2bf(float f) {
  unsigned int x = __float_as_uint(f);
  unsigned int r = (x + 0x7fffu + ((x >> 16) & 1u)) >> 16;
  return (unsigned short)r;
}
__device__ __forceinline__ float bf2f(unsigned short u) {
  return __uint_as_float(((unsigned int)u) << 16);
}

__device__ __forceinline__ void gload_lds16(const void* g, void* l) {
  __builtin_amdgcn_global_load_lds(
      (const __attribute__((address_space(1))) unsigned int*)g,
      (__attribute__((address_space(3))) unsigned int*)l,
      16, 0, 0);
}

// ---------- fused dropout + f32->bf16, zero-pad rows [NND, MPAD) ----------
__global__ void k_dropout(const float* __restrict__ x, const float* __restrict__ dm,
                          unsigned short* __restrict__ xd) {
  int idx = blockIdx.x * 256 + threadIdx.x;   // one float4 per thread
  int row = idx >> 7;
  int q = (idx & 127) << 2;
  size_t o = (size_t)row * KD + q;
  ushort4 u;
  if (row < NND) {
    float4 xv = *(const float4*)(x + o);
    float4 mv = *(const float4*)(dm + o);
    float a0 = (mv.x >= PDROP) ? xv.x * INV_KEEP : 0.0f;
    float a1 = (mv.y >= PDROP) ? xv.y * INV_KEEP : 0.0f;
    float a2 = (mv.z >= PDROP) ? xv.z * INV_KEEP : 0.0f;
    float a3 = (mv.w >= PDROP) ? xv.w * INV_KEEP : 0.0f;
    u.x = f2bf(a0); u.y = f2bf(a1); u.z = f2bf(a2); u.w = f2bf(a3);
  } else {
    u.x = 0; u.y = 0; u.z = 0; u.w = 0;
  }
  *(ushort4*)(xd + o) = u;
}

// ---------- W^T in bf16 ----------
__global__ void k_wt(const float* __restrict__ W, unsigned short* __restrict__ wt) {
  int idx = blockIdx.x * 256 + threadIdx.x;   // idx = n*512 + k
  int n = idx >> 9, k = idx & 511;
  wt[idx] = f2bf(W[k * 512 + n]);
}

// ---------- degree (edge-only) / dinv ----------
__global__ void k_deg_init(unsigned int* deg) {
  int i = blockIdx.x * 256 + threadIdx.x;
  if (i < NND) deg[i] = 0u;
}
__global__ void k_deg_count(const int* __restrict__ ei, unsigned int* deg) {
  int e = blockIdx.x * 256 + threadIdx.x;
  if (e < NED) atomicAdd(&deg[ei[NED + e]], 1u);   // col = destination
}
__global__ void k_dinv(const unsigned int* __restrict__ deg, float* __restrict__ dinv) {
  int i = blockIdx.x * 256 + threadIdx.x;
  if (i < NND) dinv[i] = rsqrtf((float)(deg[i] + 1u));  // +1 self-loop
}

// ---------- exclusive scan of deg -> offs (3 kernels) ----------
__global__ void k_scan1(const unsigned int* __restrict__ deg,
                        unsigned int* __restrict__ offs, unsigned int* __restrict__ bsum) {
  __shared__ unsigned int s[256];
  int tid = threadIdx.x;
  int i = blockIdx.x * 256 + tid;
  unsigned int v = (i < NND) ? deg[i] : 0u;
  s[tid] = v;
  __syncthreads();
  for (int d = 1; d < 256; d <<= 1) {
    unsigned int t = (tid >= d) ? s[tid - d] : 0u;
    __syncthreads();
    s[tid] += t;
    __syncthreads();
  }
  if (i < NND) offs[i] = s[tid] - v;          // block-local exclusive
  if (tid == 255) bsum[blockIdx.x] = s[255];
}
__global__ void k_scan2(unsigned int* __restrict__ bsum) {   // 391 entries, 1 block x 512
  __shared__ unsigned int s[512];
  int t = threadIdx.x;
  unsigned int v = (t < 391) ? bsum[t] : 0u;
  s[t] = v;
  __syncthreads();
  for (int d = 1; d < 512; d <<= 1) {
    unsigned int u = (t >= d) ? s[t - d] : 0u;
    __syncthreads();
    s[t] += u;
    __syncthreads();
  }
  if (t < 391) bsum[t] = s[t] - v;            // exclusive block offsets
}
__global__ void k_scan3(const unsigned int* __restrict__ bsum, unsigned int* __restrict__ offs) {
  int i = blockIdx.x * 256 + threadIdx.x;
  if (i < NND) offs[i] += bsum[blockIdx.x];
}

// ---------- CSR fill: offs acts as cursor; afterwards offs[i] == end(i) ----------
__global__ void k_fill(const int* __restrict__ ei, unsigned int* __restrict__ offs,
                       int* __restrict__ srcs) {
  int e = blockIdx.x * 256 + threadIdx.x;
  if (e < NED) {
    int dst = ei[NED + e];
    unsigned int pos = atomicAdd(&offs[dst], 1u);
    srcs[pos] = ei[e];
  }
}

// ---------- bf16 MFMA GEMM: hp = dinv_row * (xd @ W) in bf16 ----------
__launch_bounds__(256, 2)
__global__ void k_gemm(const unsigned short* __restrict__ xd,
                       const unsigned short* __restrict__ wt,
                       const float* __restrict__ dinv,
                       unsigned short* __restrict__ hp) {
  __shared__ unsigned short As[128 * 64];
  __shared__ unsigned short Bs[128 * 64];

  int bid = blockIdx.x;
  int wg = (bid & 7) * 391 + (bid >> 3);      // XCD-chunked bijective swizzle (3128 = 8*391)
  int mt = wg >> 2, nt = wg & 3;
  int t = threadIdx.x, wave = t >> 6, lane = t & 63;
  int wr = wave >> 1, wc = wave & 1;

  f32x4 zero = {0.f, 0.f, 0.f, 0.f};
  f32x4 acc[4][4];
  for (int m = 0; m < 4; ++m)
    for (int n = 0; n < 4; ++n) acc[m][n] = zero;

  const int m_base = mt * 128;
  const int n_base = nt * 128;
  const int crow = lane >> 3;
  const int ccol = (lane & 7) * 8;

  for (int kt = 0; kt < 8; ++kt) {
    int k0 = kt * 64;
    for (int i = 0; i < 4; ++i) {
      int c = i * 4 + wave;
      int r = c * 8 + crow;
      gload_lds16(xd + (size_t)(m_base + r) * KD + k0 + ccol, As + c * 512);
      gload_lds16(wt + (size_t)(n_base + r) * KD + k0 + ccol, Bs + c * 512);
    }
    __syncthreads();
    for (int kk = 0; kk < 2; ++kk) {
      int ko = kk * 32 + (lane >> 4) * 8;
      short8 a[4], b[4];
      for (int m = 0; m < 4; ++m)
        a[m] = *(const short8*)(As + (wr * 64 + m * 16 + (lane & 15)) * 64 + ko);
      for (int n = 0; n < 4; ++n)
        b[n] = *(const short8*)(Bs + (wc * 64 + n * 16 + (lane & 15)) * 64 + ko);
      for (int m = 0; m < 4; ++m)
        for (int n = 0; n < 4; ++n)
          acc[m][n] = __builtin_amdgcn_mfma_f32_16x16x32_bf16(a[m], b[n], acc[m][n], 0, 0, 0);
    }
    __syncthreads();
  }

  // epilogue: C/D layout col=lane&15, row=(lane>>4)*4+j; scale by dinv[row]
  int c0 = n_base + wc * 64;
  for (int m = 0; m < 4; ++m) {
    int grb = m_base + wr * 64 + m * 16 + (lane >> 4) * 4;
    for (int j = 0; j < 4; ++j) {
      int gr = grb + j;
      if (gr < NND) {
        float dv = dinv[gr];
        size_t ro = (size_t)gr * ND;
        for (int n = 0; n < 4; ++n) {
          int gc = c0 + n * 16 + (lane & 15);
          hp[ro + gc] = f2bf(acc[m][n][j] * dv);
        }
      }
    }
  }
}

// ---------- gather-aggregate: one wave per node ----------
// out[i] = dinv[i] * (hp[i] + sum_{e: dst=i} hp[src]) + b
__global__ void k_aggregate(const unsigned int* __restrict__ ends,   // offs after fill = end
                            const unsigned int* __restrict__ deg,
                            const int* __restrict__ srcs,
                            const unsigned short* __restrict__ hp,
                            const float* __restrict__ dinv,
                            const float* __restrict__ b,
                            float* __restrict__ out) {
  int node = blockIdx.x * 4 + (threadIdx.x >> 6);
  if (node >= NND) return;
  int lane = threadIdx.x & 63;
  int q = lane * 8;                       // 8 f32 per lane, 64 lanes = 512 cols

  float acc[8];
  ushort8 hs = *(const ushort8*)(hp + (size_t)node * ND + q);   // self-loop
  #pragma unroll
  for (int j = 0; j < 8; ++j) acc[j] = bf2f(hs[j]);

  unsigned int d = deg[node];
  unsigned int end = ends[node];
  unsigned int beg = end - d;
  for (unsigned int e = beg; e < end; ++e) {
    int s = srcs[e];
    ushort8 hv = *(const ushort8*)(hp + (size_t)s * ND + q);
    #pragma unroll
    for (int j = 0; j < 8; ++j) acc[j] += bf2f(hv[j]);
  }

  float dv = dinv[node];
  float4 b0 = *(const float4*)(b + q);
  float4 b1 = *(const float4*)(b + q + 4);
  float4 o0, o1;
  o0.x = acc[0] * dv + b0.x; o0.y = acc[1] * dv + b0.y;
  o0.z = acc[2] * dv + b0.z; o0.w = acc[3] * dv + b0.w;
  o1.x = acc[4] * dv + b1.x; o1.y = acc[5] * dv + b1.y;
  o1.z = acc[6] * dv + b1.z; o1.w = acc[7] * dv + b1.w;
  float* op = out + (size_t)node * ND + q;
  *(float4*)op = o0;
  *(float4*)(op + 4) = o1;
}

extern "C" void kernel_launch(void* const* d_in, const int* in_sizes, int n_in,
                              void* d_out, int out_size, void* d_ws, size_t ws_size,
                              hipStream_t stream) {
  const float* x  = (const float*)d_in[0];
  const int*   ei = (const int*)d_in[1];     // int64 in reference -> int32 in harness
  const float* W  = (const float*)d_in[2];
  const float* b  = (const float*)d_in[3];
  const float* dm = (const float*)d_in[4];
  float* out = (float*)d_out;

  char* ws = (char*)d_ws;
  unsigned short* xd   = (unsigned short*)(ws + XD_OFF);
  unsigned short* wt   = (unsigned short*)(ws + WT_OFF);
  unsigned short* hp   = (unsigned short*)(ws + HP_OFF);
  unsigned int*   deg  = (unsigned int*)(ws + DEG_OFF);
  float*          dinv = (float*)(ws + DINV_OFF);
  unsigned int*   offs = (unsigned int*)(ws + OFFS_OFF);
  int*            srcs = (int*)(ws + SRCS_OFF);
  unsigned int*   bsum = (unsigned int*)(ws + BSUM_OFF);

  hipLaunchKernelGGL(k_dropout,   dim3(50048), dim3(256), 0, stream, x, dm, xd);
  hipLaunchKernelGGL(k_wt,        dim3(1024),  dim3(256), 0, stream, W, wt);
  hipLaunchKernelGGL(k_deg_init,  dim3(391),   dim3(256), 0, stream, deg);
  hipLaunchKernelGGL(k_deg_count, dim3(1563),  dim3(256), 0, stream, ei, deg);
  hipLaunchKernelGGL(k_dinv,      dim3(391),   dim3(256), 0, stream, deg, dinv);
  hipLaunchKernelGGL(k_scan1,     dim3(391),   dim3(256), 0, stream, deg, offs, bsum);
  hipLaunchKernelGGL(k_scan2,     dim3(1),     dim3(512), 0, stream, bsum);
  hipLaunchKernelGGL(k_scan3,     dim3(391),   dim3(256), 0, stream, bsum, offs);
  hipLaunchKernelGGL(k_fill,      dim3(1563),  dim3(256), 0, stream, ei, offs, srcs);
  hipLaunchKernelGGL(k_gemm,      dim3(3128),  dim3(256), 0, stream, xd, wt, dinv, hp);
  hipLaunchKernelGGL(k_aggregate, dim3(25000), dim3(256), 0, stream, offs, deg, srcs, hp, dinv, b, out);
}

// Round 4
// 333.728 us; speedup vs baseline: 8.8335x; 1.0422x over previous
//
#include <hip/hip_runtime.h>
#include <hip/hip_bf16.h>
#include <stdint.h>

// Problem constants
#define NND   100000      // nodes
#define NED   400000      // edges
#define KD    512         // DIN
#define ND    512         // DOUT
#define MPAD  100096      // 782 * 128
#define PDROP 0.1f
#define INV_KEEP (1.0f/0.9f)

#define BM  128
#define BKF 32            // K per step
#define NT  16            // 512/32 K-steps

typedef __attribute__((ext_vector_type(4))) float f32x4;
typedef __attribute__((ext_vector_type(8))) short short8;
typedef __attribute__((ext_vector_type(8))) unsigned short ushort8;

// ---- ws layout (bytes) ----
#define WT_OFF   102498304    // wt_bf16 [512][512]   = 524,288  (keep legacy offsets)
#define HP_OFF   103022592    // hp_bf16 [MPAD][512]  = 102,498,304
#define DEG_OFF  205520896    // deg_u32 [NND]
#define DINV_OFF 205920896    // dinv_f32[NND]
#define OFFS_OFF 206320896    // offs_u32[NND] (CSR cursor -> ends)
#define SRCS_OFF 206720896    // srcs_i32[NED]
#define BSUM_OFF 208320896    // block sums

__device__ __forceinline__ unsigned short f2bf(float f) {
  unsigned int x = __float_as_uint(f);
  unsigned int r = (x + 0x7fffu + ((x >> 16) & 1u)) >> 16;
  return (unsigned short)r;
}
__device__ __forceinline__ float bf2f(unsigned short u) {
  return __uint_as_float(((unsigned int)u) << 16);
}
__device__ __forceinline__ void gload_lds16(const void* g, void* l) {
  __builtin_amdgcn_global_load_lds(
      (const __attribute__((address_space(1))) unsigned int*)g,
      (__attribute__((address_space(3))) unsigned int*)l,
      16, 0, 0);
}

// ---------- W^T in bf16 ----------
__global__ void k_wt(const float* __restrict__ W, unsigned short* __restrict__ wt) {
  int idx = blockIdx.x * 256 + threadIdx.x;   // idx = n*512 + k
  int n = idx >> 9, k = idx & 511;
  wt[idx] = f2bf(W[k * 512 + n]);
}

// ---------- degree count (deg pre-zeroed by memset) ----------
__global__ void k_deg_count(const int* __restrict__ ei, unsigned int* deg) {
  int e = blockIdx.x * 256 + threadIdx.x;
  if (e < NED) atomicAdd(&deg[ei[NED + e]], 1u);   // col = destination
}

// ---------- exclusive scan of deg -> offs (+ dinv fused) ----------
__global__ void k_scan1(const unsigned int* __restrict__ deg,
                        unsigned int* __restrict__ offs, unsigned int* __restrict__ bsum,
                        float* __restrict__ dinv) {
  __shared__ unsigned int s[256];
  int tid = threadIdx.x;
  int i = blockIdx.x * 256 + tid;
  unsigned int v = (i < NND) ? deg[i] : 0u;
  if (i < NND) dinv[i] = rsqrtf((float)(v + 1u));   // +1 self-loop
  s[tid] = v;
  __syncthreads();
  for (int d = 1; d < 256; d <<= 1) {
    unsigned int t = (tid >= d) ? s[tid - d] : 0u;
    __syncthreads();
    s[tid] += t;
    __syncthreads();
  }
  if (i < NND) offs[i] = s[tid] - v;
  if (tid == 255) bsum[blockIdx.x] = s[255];
}
__global__ void k_scan2(unsigned int* __restrict__ bsum) {   // 391 entries
  __shared__ unsigned int s[512];
  int t = threadIdx.x;
  unsigned int v = (t < 391) ? bsum[t] : 0u;
  s[t] = v;
  __syncthreads();
  for (int d = 1; d < 512; d <<= 1) {
    unsigned int u = (t >= d) ? s[t - d] : 0u;
    __syncthreads();
    s[t] += u;
    __syncthreads();
  }
  if (t < 391) bsum[t] = s[t] - v;
}
__global__ void k_scan3(const unsigned int* __restrict__ bsum, unsigned int* __restrict__ offs) {
  int i = blockIdx.x * 256 + threadIdx.x;
  if (i < NND) offs[i] += bsum[blockIdx.x];
}

// ---------- CSR fill: offs acts as cursor; afterwards offs[i] == end(i) ----------
__global__ void k_fill(const int* __restrict__ ei, unsigned int* __restrict__ offs,
                       int* __restrict__ srcs) {
  int e = blockIdx.x * 256 + threadIdx.x;
  if (e < NED) {
    int dst = ei[NED + e];
    unsigned int pos = atomicAdd(&offs[dst], 1u);
    srcs[pos] = ei[e];
  }
}

// ---------- fused dropout + bf16 MFMA GEMM: hp = dinv_row * (dropout(x) @ W) ----------
// BM=128 x BN=512 (full width, A read once), BK=32, 512 thr = 8 waves (2M x 4N),
// per-wave 64x128 out = acc[4][8]. A: f32 global->reg->dropout->ds_write (T14).
// B: global_load_lds from precvt wt. Double-buffered LDS 80 KB, 1 barrier/step.
__launch_bounds__(512, 2)
__global__ void k_fused(const float* __restrict__ x, const float* __restrict__ dm,
                        const unsigned short* __restrict__ wt,
                        const float* __restrict__ dinv,
                        unsigned short* __restrict__ hp) {
  __shared__ unsigned short As[2][BM * BKF];    // 8 KB each
  __shared__ unsigned short Bs[2][512 * BKF];   // 32 KB each

  int t = threadIdx.x, wave = t >> 6, lane = t & 63;
  int wm = wave >> 2, wn = wave & 3;
  int mb = blockIdx.x * BM;

  // A staging: thread t -> row t>>2 (0..127), cols (t&3)*8 (8 f32)
  int ar = t >> 2;
  int ac = (t & 3) * 8;
  bool arow_ok = (mb + ar) < NND;
  size_t arow = arow_ok ? (size_t)(mb + ar) : 0;
  const float* xp = x + arow * KD + ac;
  const float* mp = dm + arow * KD + ac;
  unsigned short* awr0 = &As[0][ar * BKF + ac];
  unsigned short* awr1 = &As[1][ar * BKF + ac];

  f32x4 zero = {0.f, 0.f, 0.f, 0.f};
  f32x4 acc[4][8];
  #pragma unroll
  for (int m = 0; m < 4; ++m)
    #pragma unroll
    for (int n = 0; n < 8; ++n) acc[m][n] = zero;

  float4 xv0, xv1, mv0, mv1;

  // ---- prologue: stage step 0 ----
  xv0 = *(const float4*)(xp);     xv1 = *(const float4*)(xp + 4);
  mv0 = *(const float4*)(mp);     mv1 = *(const float4*)(mp + 4);
  #pragma unroll
  for (int i = 0; i < 4; ++i) {
    int ci = i * 512 + t;
    gload_lds16(wt + (size_t)(ci >> 2) * KD + ((ci & 3) * 8), &Bs[0][ci * 8]);
  }
  {
    ushort8 u;
    const float* xs = (const float*)&xv0; const float* ms = (const float*)&mv0;
    #pragma unroll
    for (int j = 0; j < 4; ++j) u[j] = (arow_ok && ms[j] >= PDROP) ? f2bf(xs[j] * INV_KEEP) : 0;
    xs = (const float*)&xv1; ms = (const float*)&mv1;
    #pragma unroll
    for (int j = 0; j < 4; ++j) u[4 + j] = (arow_ok && ms[j] >= PDROP) ? f2bf(xs[j] * INV_KEEP) : 0;
    *(ushort8*)awr0 = u;
  }
  __syncthreads();

  int cur = 0;
  for (int kt = 0; kt < NT; ++kt) {
    int k0n = (kt + 1) * BKF;
    if (kt + 1 < NT) {
      // issue next A loads FIRST (so the pre-ds_write wait is vmcnt(4), not 0)
      xv0 = *(const float4*)(xp + k0n);     xv1 = *(const float4*)(xp + k0n + 4);
      mv0 = *(const float4*)(mp + k0n);     mv1 = *(const float4*)(mp + k0n + 4);
      #pragma unroll
      for (int i = 0; i < 4; ++i) {
        int ci = i * 512 + t;
        gload_lds16(wt + (size_t)(ci >> 2) * KD + k0n + ((ci & 3) * 8), &Bs[cur ^ 1][ci * 8]);
      }
    }
    // compute on buf[cur]
    short8 a[4], b[8];
    int fr = (lane & 15);
    int ko = (lane >> 4) * 8;
    #pragma unroll
    for (int m = 0; m < 4; ++m)
      a[m] = *(const short8*)(&As[cur][(wm * 64 + m * 16 + fr) * BKF + ko]);
    #pragma unroll
    for (int n = 0; n < 8; ++n)
      b[n] = *(const short8*)(&Bs[cur][(wn * 128 + n * 16 + fr) * BKF + ko]);
    #pragma unroll
    for (int m = 0; m < 4; ++m)
      #pragma unroll
      for (int n = 0; n < 8; ++n)
        acc[m][n] = __builtin_amdgcn_mfma_f32_16x16x32_bf16(a[m], b[n], acc[m][n], 0, 0, 0);
    if (kt + 1 < NT) {
      ushort8 u;
      const float* xs = (const float*)&xv0; const float* ms = (const float*)&mv0;
      #pragma unroll
      for (int j = 0; j < 4; ++j) u[j] = (arow_ok && ms[j] >= PDROP) ? f2bf(xs[j] * INV_KEEP) : 0;
      xs = (const float*)&xv1; ms = (const float*)&mv1;
      #pragma unroll
      for (int j = 0; j < 4; ++j) u[4 + j] = (arow_ok && ms[j] >= PDROP) ? f2bf(xs[j] * INV_KEEP) : 0;
      *(ushort8*)((cur == 0) ? awr1 : awr0) = u;
    }
    __syncthreads();
    cur ^= 1;
  }

  // epilogue: C/D layout col=lane&15, row=(lane>>4)*4+j; scale by dinv[row]
  int c0 = wn * 128 + (lane & 15);
  #pragma unroll
  for (int m = 0; m < 4; ++m) {
    int grb = mb + wm * 64 + m * 16 + (lane >> 4) * 4;
    #pragma unroll
    for (int j = 0; j < 4; ++j) {
      int gr = grb + j;
      if (gr < NND) {
        float dv = dinv[gr];
        size_t ro = (size_t)gr * ND + c0;
        #pragma unroll
        for (int n = 0; n < 8; ++n)
          hp[ro + n * 16] = f2bf(acc[m][n][j] * dv);
      }
    }
  }
}

// ---------- gather-aggregate: one wave per node ----------
__global__ void k_aggregate(const unsigned int* __restrict__ ends,
                            const unsigned int* __restrict__ deg,
                            const int* __restrict__ srcs,
                            const unsigned short* __restrict__ hp,
                            const float* __restrict__ dinv,
                            const float* __restrict__ b,
                            float* __restrict__ out) {
  int node = blockIdx.x * 4 + (threadIdx.x >> 6);
  if (node >= NND) return;
  int lane = threadIdx.x & 63;
  int q = lane * 8;

  float acc[8];
  ushort8 hs = *(const ushort8*)(hp + (size_t)node * ND + q);   // self-loop
  #pragma unroll
  for (int j = 0; j < 8; ++j) acc[j] = bf2f(hs[j]);

  unsigned int d = deg[node];
  unsigned int end = ends[node];
  unsigned int beg = end - d;
  for (unsigned int e = beg; e < end; ++e) {
    int s = srcs[e];
    ushort8 hv = *(const ushort8*)(hp + (size_t)s * ND + q);
    #pragma unroll
    for (int j = 0; j < 8; ++j) acc[j] += bf2f(hv[j]);
  }

  float dv = dinv[node];
  float4 b0 = *(const float4*)(b + q);
  float4 b1 = *(const float4*)(b + q + 4);
  float4 o0, o1;
  o0.x = acc[0] * dv + b0.x; o0.y = acc[1] * dv + b0.y;
  o0.z = acc[2] * dv + b0.z; o0.w = acc[3] * dv + b0.w;
  o1.x = acc[4] * dv + b1.x; o1.y = acc[5] * dv + b1.y;
  o1.z = acc[6] * dv + b1.z; o1.w = acc[7] * dv + b1.w;
  float* op = out + (size_t)node * ND + q;
  *(float4*)op = o0;
  *(float4*)(op + 4) = o1;
}

extern "C" void kernel_launch(void* const* d_in, const int* in_sizes, int n_in,
                              void* d_out, int out_size, void* d_ws, size_t ws_size,
                              hipStream_t stream) {
  const float* x  = (const float*)d_in[0];
  const int*   ei = (const int*)d_in[1];     // int64 in reference -> int32 in harness
  const float* W  = (const float*)d_in[2];
  const float* b  = (const float*)d_in[3];
  const float* dm = (const float*)d_in[4];
  float* out = (float*)d_out;

  char* ws = (char*)d_ws;
  unsigned short* wt   = (unsigned short*)(ws + WT_OFF);
  unsigned short* hp   = (unsigned short*)(ws + HP_OFF);
  unsigned int*   deg  = (unsigned int*)(ws + DEG_OFF);
  float*          dinv = (float*)(ws + DINV_OFF);
  unsigned int*   offs = (unsigned int*)(ws + OFFS_OFF);
  int*            srcs = (int*)(ws + SRCS_OFF);
  unsigned int*   bsum = (unsigned int*)(ws + BSUM_OFF);

  hipMemsetAsync(deg, 0, NND * sizeof(unsigned int), stream);
  hipLaunchKernelGGL(k_wt,        dim3(1024),  dim3(256), 0, stream, W, wt);
  hipLaunchKernelGGL(k_deg_count, dim3(1563),  dim3(256), 0, stream, ei, deg);
  hipLaunchKernelGGL(k_scan1,     dim3(391),   dim3(256), 0, stream, deg, offs, bsum, dinv);
  hipLaunchKernelGGL(k_scan2,     dim3(1),     dim3(512), 0, stream, bsum);
  hipLaunchKernelGGL(k_scan3,     dim3(391),   dim3(256), 0, stream, bsum, offs);
  hipLaunchKernelGGL(k_fill,      dim3(1563),  dim3(256), 0, stream, ei, offs, srcs);
  hipLaunchKernelGGL(k_fused,     dim3(782),   dim3(512), 0, stream, x, dm, wt, dinv, hp);
  hipLaunchKernelGGL(k_aggregate, dim3(25000), dim3(256), 0, stream, offs, deg, srcs, hp, dinv, b, out);
}